// Round 1
// baseline (508.014 us; speedup 1.0000x reference)
//
#include <hip/hip_runtime.h>
#include <hip/hip_bf16.h>

// Problem constants (from reference: B=4, C=64, H=W=512, K=8)
#define KWIN 8
constexpr int BB = 4, CC = 64, HH = 512, WW = 512;
constexpr int NH = HH / KWIN;            // 64
constexpr int NW = WW / KWIN;            // 64
constexpr int NWIN = NH * NW;            // 4096 windows per batch
constexpr int MCOL = (CC * NWIN) / 2;    // 131072 columns per output array
constexpr size_t ZOFF = (size_t)BB * KWIN * KWIN * MCOL;  // flat offset of zeros array

// ---------------------------------------------------------------------------
// Kernel 1: per-window flag (any mask element > 0) + exclusive prefix rank per
// batch. Packed as rank | (flag<<31) into ws. One block per batch.
// ---------------------------------------------------------------------------
__global__ __launch_bounds__(1024) void compute_ranks(
    const float* __restrict__ mask, int* __restrict__ rankPacked,
    int* __restrict__ OnOut) {
  const int b = blockIdx.x;
  const int t = threadIdx.x;
  const int lane = t & 63;
  const int wid = t >> 6;
  __shared__ int waveSums[16];

  int flags[4];
  int cnt = 0;
#pragma unroll
  for (int i = 0; i < 4; ++i) {
    int n = t * 4 + i;                  // window index 0..4095
    int ph = n >> 6, pw = n & 63;
    const float* base = mask + ((size_t)b * HH + ph * KWIN) * WW + pw * KWIN;
    bool any = false;
#pragma unroll
    for (int kh = 0; kh < KWIN; ++kh) {
      const float4* rp = (const float4*)(base + (size_t)kh * WW);
      float4 a = rp[0], q = rp[1];
      any = any || a.x > 0.f || a.y > 0.f || a.z > 0.f || a.w > 0.f ||
            q.x > 0.f || q.y > 0.f || q.z > 0.f || q.w > 0.f;
    }
    flags[i] = any ? 1 : 0;
    cnt += flags[i];
  }

  // inclusive wave scan (wave = 64 lanes)
  int inc = cnt;
#pragma unroll
  for (int off = 1; off < 64; off <<= 1) {
    int up = __shfl_up(inc, off);
    if (lane >= off) inc += up;
  }
  if (lane == 63) waveSums[wid] = inc;
  __syncthreads();
  if (wid == 0 && lane < 16) {
    int v = waveSums[lane];
#pragma unroll
    for (int off = 1; off < 16; off <<= 1) {
      int up = __shfl_up(v, off);
      if (lane >= off) v += up;
    }
    waveSums[lane] = v;
  }
  __syncthreads();
  int waveOff = (wid == 0) ? 0 : waveSums[wid - 1];
  int run = waveOff + inc - cnt;        // exclusive prefix for this thread
#pragma unroll
  for (int i = 0; i < 4; ++i) {
    int n = t * 4 + i;
    rankPacked[b * NWIN + n] =
        (int)((unsigned)run | (flags[i] ? 0x80000000u : 0u));
    run += flags[i];
  }
  if (t == 1023) OnOut[b] = run;        // total ones count for batch
}

// LDS swizzle: XOR bits [4:2] of the within-row float index with (w>>6)&7.
// Keeps 4-float groups contiguous (float4 stores OK) and spreads the
// stride-64-float gather across 8 banks (2-way aliasing = free).
__device__ __forceinline__ int swz(int w) {
  return w ^ (((w >> 6) & 7) << 2);
}

// ---------------------------------------------------------------------------
// Kernel 2: the permutation. One block per (b, c, ph) strip:
//  - stage contiguous 8x512 float strip -> LDS (swizzled)
//  - build row's ones-then-zeros pw list via ballot (ranks within a row are
//    contiguous because global window order is row-major)
//  - each thread gathers 4 floats for one (r, 4-column group) and stores a
//    coalesced float4
// ---------------------------------------------------------------------------
__global__ __launch_bounds__(256) void scatter_perm(
    const float* __restrict__ x, const int* __restrict__ rankPacked,
    const int* __restrict__ OnArr, float* __restrict__ out) {
  const int bid = blockIdx.x;
  const int ph = bid & (NH - 1);
  const int c = (bid >> 6) & (CC - 1);
  const int b = bid >> 12;
  const int t = threadIdx.x;

  __shared__ float lds[KWIN * WW];      // 16 KB, swizzled layout
  __shared__ int s_pw[NW];              // ones pw's [0,cntOnes), zeros after
  __shared__ int s_meta[4];             // cntOnes, baseOnes, baseZeros, On

  // ---- stage input (rows ph*8..ph*8+7 are contiguous: one 16 KB block) ----
  const float4* src =
      (const float4*)(x + ((size_t)(b * CC + c) * HH + ph * KWIN) * WW);
#pragma unroll
  for (int v = 0; v < 4; ++v) {
    int i = v * 256 + t;                // float4 index 0..1023
    float4 val = src[i];
    int kh = i >> 7;
    int w = (i & 127) << 2;
    *(float4*)&lds[kh * WW + swz(w)] = val;
  }

  if (t < NW) {                         // exactly wave 0
    unsigned rp = (unsigned)rankPacked[b * NWIN + ph * NW + t];
    int flag = (int)(rp >> 31);
    int rank = (int)(rp & 0x7fffffffu);
    unsigned long long bal = __ballot(flag);
    int cntOnes = __popcll(bal);
    int below = __popcll(bal & ((1ull << t) - 1ull));
    if (flag) s_pw[below] = t;
    else s_pw[cntOnes + (t - below)] = t;
    if (t == 0) {
      s_meta[0] = cntOnes;
      s_meta[1] = rank;                 // ones before this row
      s_meta[2] = ph * NW - rank;       // zeros before this row
      s_meta[3] = OnArr[b];
    }
  }
  __syncthreads();

  const int cntOnes = s_meta[0];
  const int baseOnes = s_meta[1];
  const int baseZeros = s_meta[2];
  const int On = s_meta[3];
  const int Oz = NWIN - On;
  const bool al1 = ((c * On + baseOnes) & 3) == 0;
  const bool al2 = ((c * Oz + baseZeros) & 3) == 0;

#pragma unroll
  for (int v = 0; v < 4; ++v) {
    int idx = v * 256 + t;              // 0..1023 = 64 r x 16 groups
    int r = idx >> 4;                   // output row kh*8+kw
    int j0 = (idx & 15) << 2;           // first of 4 columns in this row
    int kh = r >> 3, kw = r & 7;

    float vals[4];
#pragma unroll
    for (int u = 0; u < 4; ++u) {
      int pw = s_pw[j0 + u];
      vals[u] = lds[kh * WW + swz(pw * KWIN + kw)];
    }

    size_t rowOff = (size_t)(b * (KWIN * KWIN) + r) * MCOL;
    if (j0 + 3 < cntOnes) {             // all 4 in ones section
      float* p = out + rowOff + (size_t)c * On + (baseOnes + j0);
      if (al1)
        *(float4*)p = make_float4(vals[0], vals[1], vals[2], vals[3]);
      else {
        p[0] = vals[0]; p[1] = vals[1]; p[2] = vals[2]; p[3] = vals[3];
      }
    } else if (j0 >= cntOnes) {         // all 4 in zeros section
      float* p = out + ZOFF + rowOff + (size_t)c * Oz +
                 (baseZeros + (j0 - cntOnes));
      if (al2)
        *(float4*)p = make_float4(vals[0], vals[1], vals[2], vals[3]);
      else {
        p[0] = vals[0]; p[1] = vals[1]; p[2] = vals[2]; p[3] = vals[3];
      }
    } else {                            // straddles sections: scalar stores
#pragma unroll
      for (int u = 0; u < 4; ++u) {
        int j = j0 + u;
        if (j < cntOnes)
          out[rowOff + (size_t)c * On + (baseOnes + j)] = vals[u];
        else
          out[ZOFF + rowOff + (size_t)c * Oz +
              (baseZeros + (j - cntOnes))] = vals[u];
      }
    }
  }
}

extern "C" void kernel_launch(void* const* d_in, const int* in_sizes, int n_in,
                              void* d_out, int out_size, void* d_ws,
                              size_t ws_size, hipStream_t stream) {
  const float* mask = (const float*)d_in[0];
  const float* x = (const float*)d_in[1];
  float* out = (float*)d_out;

  int* rankPacked = (int*)d_ws;                 // BB*NWIN ints
  int* OnArr = rankPacked + BB * NWIN;          // BB ints

  compute_ranks<<<BB, 1024, 0, stream>>>(mask, rankPacked, OnArr);
  scatter_perm<<<BB * CC * NH, 256, 0, stream>>>(x, rankPacked, OnArr, out);
}

// Round 2
// 458.791 us; speedup vs baseline: 1.1073x; 1.1073x over previous
//
#include <hip/hip_runtime.h>
#include <hip/hip_bf16.h>

// Problem constants (B=4, C=64, H=W=512, K=8)
#define KWIN 8
constexpr int BB = 4, CC = 64, HH = 512, WW = 512;
constexpr int NH = HH / KWIN;            // 64 window rows
constexpr int NW = WW / KWIN;            // 64 window cols
constexpr int NWIN = NH * NW;            // 4096 windows per batch
constexpr int MCOL = (CC * NWIN) / 2;    // 131072 output columns per array
constexpr size_t ZOFF = (size_t)BB * KWIN * KWIN * MCOL;  // zeros array offset
constexpr int PHG = 4;                   // window-rows per scatter block

// Involution swizzle on float index within a 512-float image row:
// XOR bits [4:2] with bits [8:6]. Keeps float4 groups intact.
__device__ __forceinline__ int swz(int w) {
  return w ^ (((w >> 6) & 7) << 2);
}

// ---------------------------------------------------------------------------
// Kernel 1: one wave per (b, window-row). Lane pw checks its 8x8 window for
// any mask>0; ballot -> u64 rowMask. 256 blocks -> latency well hidden.
// ---------------------------------------------------------------------------
__global__ __launch_bounds__(64) void row_flags(
    const float* __restrict__ mask, unsigned long long* __restrict__ rowMask) {
  const int ph = blockIdx.x & (NH - 1);
  const int b = blockIdx.x >> 6;
  const int pw = threadIdx.x;
  const float* base = mask + ((size_t)b * HH + ph * KWIN) * WW + pw * KWIN;
  bool any = false;
#pragma unroll
  for (int kh = 0; kh < KWIN; ++kh) {
    const float4* rp = (const float4*)(base + (size_t)kh * WW);
    float4 a = rp[0], q = rp[1];
    any = any || a.x > 0.f || a.y > 0.f || a.z > 0.f || a.w > 0.f ||
          q.x > 0.f || q.y > 0.f || q.z > 0.f || q.w > 0.f;
  }
  unsigned long long bal = __ballot(any);
  if (pw == 0) rowMask[blockIdx.x] = bal;
}

// ---------------------------------------------------------------------------
// Kernel 2: permutation. One block per (b, c, group-of-4 window-rows):
//  - stage 64 KB contiguous strip -> swizzled LDS (2 blocks/CU)
//  - rebuild global ones-prefix from the 64 u64 rowMasks (wave 0)
//  - build per-row compacted pw lists (threads 64..319)
//  - gather: wave = {4 consecutive r} x {1 ph-row} x {16 col-groups}
//    -> 2-way LDS banks (free), 512B contiguous write segments per section
// ---------------------------------------------------------------------------
__global__ __launch_bounds__(512) void scatter_perm(
    const float* __restrict__ x, const unsigned long long* __restrict__ rowMask,
    float* __restrict__ out) {
  const int bid = blockIdx.x;
  const int pg = bid & (NH / PHG - 1);   // 0..15 : which group of 4 rows
  const int c = (bid >> 4) & (CC - 1);
  const int b = bid >> 10;
  const int t = threadIdx.x;

  __shared__ float lds[PHG * KWIN * WW];         // 64 KB
  __shared__ unsigned char s_pw[PHG][NW];        // compacted pw lists
  __shared__ int s_cnt[PHG], s_base1[PHG];       // per-row ones cnt / prefix
  __shared__ int s_On;                           // batch total ones

  // ---- issue the 64 KB contiguous read (8 float4 / thread) ----
  const float* src = x + ((size_t)(b * CC + c) * HH + pg * (PHG * KWIN)) * WW;
  float4 stage[8];
#pragma unroll
  for (int vv = 0; vv < 8; ++vv) {
    stage[vv] = ((const float4*)src)[vv * 512 + t];
  }

  // ---- metadata while loads are in flight ----
  if (t < 64) {
    // wave 0: scan all 64 row counts for this batch -> global ones prefix
    unsigned long long m = rowMask[b * NH + t];
    int cnt = __popcll(m);
    int inc = cnt;
#pragma unroll
    for (int off = 1; off < 64; off <<= 1) {
      int up = __shfl_up(inc, off);
      if (t >= off) inc += up;
    }
    int excl = inc - cnt;                        // ones before row t
    int loc = t - pg * PHG;
    if (loc >= 0 && loc < PHG) s_base1[loc] = excl;
    if (t == 63) s_On = excl + cnt;
  } else if (t < 320) {
    int tt = t - 64;                             // 0..255
    int phl = tt >> 6, j = tt & 63;
    unsigned long long m = rowMask[b * NH + pg * PHG + phl];
    int flag = (int)((m >> j) & 1ull);
    int below = __popcll(m & ((1ull << j) - 1ull));
    int cntO = __popcll(m);
    int pos = flag ? below : cntO + j - below;
    s_pw[phl][pos] = (unsigned char)j;
    if (j == 0) s_cnt[phl] = cntO;
  }

  // ---- LDS stores (swizzled layout) ----
#pragma unroll
  for (int vv = 0; vv < 8; ++vv) {
    int i = vv * 512 + t;
    int row = i >> 7;                            // strip row 0..31
    int w = (i & 127) << 2;
    *(float4*)&lds[row * WW + swz(w)] = stage[vv];
  }
  __syncthreads();

  const int On = s_On;
  const int Oz = NWIN - On;

  // ---- gather + scatter-write ----
#pragma unroll
  for (int v = 0; v < 8; ++v) {
    int idx = v * 512 + t;                       // 0..4095 float4 units
    int g = idx & 15;                            // col group (j0 = 4g)
    int rlo = (idx >> 4) & 3;
    int phl = (idx >> 6) & 3;
    int rhi = idx >> 8;                          // 0..15
    int r = rhi * 4 + rlo;                       // output row kh*8+kw
    int kh = r >> 3, kw = r & 7;
    int row = phl * KWIN + kh;
    int j0 = g * 4;

    float vals[4];
#pragma unroll
    for (int u = 0; u < 4; ++u) {
      int pw = s_pw[phl][j0 + u];
      vals[u] = lds[row * WW + swz(pw * KWIN + kw)];
    }

    int cntO = s_cnt[phl];
    int baseO = s_base1[phl];
    int baseZ = (pg * PHG + phl) * NW - baseO;   // zeros before this row
    size_t rowOff = (size_t)(b * (KWIN * KWIN) + r) * MCOL;

    if (j0 + 3 < cntO) {                         // all 4 in ones section
      long col = (long)c * On + baseO + j0;
      float* p = out + rowOff + col;
      if ((col & 3) == 0)
        *(float4*)p = make_float4(vals[0], vals[1], vals[2], vals[3]);
      else {
        p[0] = vals[0]; p[1] = vals[1]; p[2] = vals[2]; p[3] = vals[3];
      }
    } else if (j0 >= cntO) {                     // all 4 in zeros section
      long col = (long)c * Oz + baseZ + (j0 - cntO);
      float* p = out + ZOFF + rowOff + col;
      if ((col & 3) == 0)
        *(float4*)p = make_float4(vals[0], vals[1], vals[2], vals[3]);
      else {
        p[0] = vals[0]; p[1] = vals[1]; p[2] = vals[2]; p[3] = vals[3];
      }
    } else {                                     // straddle: scalar stores
#pragma unroll
      for (int u = 0; u < 4; ++u) {
        int j = j0 + u;
        if (j < cntO)
          out[rowOff + (size_t)((long)c * On + baseO + j)] = vals[u];
        else
          out[ZOFF + rowOff + (size_t)((long)c * Oz + baseZ + (j - cntO))] =
              vals[u];
      }
    }
  }
}

extern "C" void kernel_launch(void* const* d_in, const int* in_sizes, int n_in,
                              void* d_out, int out_size, void* d_ws,
                              size_t ws_size, hipStream_t stream) {
  const float* mask = (const float*)d_in[0];
  const float* x = (const float*)d_in[1];
  float* out = (float*)d_out;
  unsigned long long* rowMask = (unsigned long long*)d_ws;  // 256 u64 = 2 KB

  row_flags<<<BB * NH, 64, 0, stream>>>(mask, rowMask);
  scatter_perm<<<BB * CC * (NH / PHG), 512, 0, stream>>>(x, rowMask, out);
}